// Round 8
// baseline (370.236 us; speedup 1.0000x reference)
//
#include <hip/hip_runtime.h>

// RWKV6 TimeMix on MI355X — R8: C=32 chunking (2x scan TLP, half serial
// depth), w restored to fp32 (isolates R6/R7 gemm anomaly), triple-buffer
// distance-3 GEMM unchanged.
//   K0 prep_w     : 5 weight matrices fp32 -> bf16
//   K1 prep_mix   : token-shift mix -> xr,xk,xv,xw (bf16)
//   K2 gemm4_bt   : 4x MFMA GEMM + activations -> r,k,v (bf16), w (fp32)
//   K3 scan_intra : chunked (C=32) scan -> o_intra (fp32), rd (bf16), U_c, D_c
//   K4 state_prop : S_{c+1} = D_c*S_c + U_c over NC=32 (U slot -> chunk-initial S_c)
//   K5 inter_ln   : O = o_intra + RD@S_c (MFMA, 2 chunks/block), LN, *r -> bf16
//   K6 gemm_out   : MFMA GEMM -> d_out (fp32)
//
// Shapes: B=4, T=1024, D=1024, H=16, DH=64. Chunks: NC=32, C=32.

typedef unsigned short u16;
typedef unsigned int   u32;

typedef __attribute__((ext_vector_type(8))) __bf16 bf16x8;
typedef __attribute__((ext_vector_type(4))) float   f32x4;

#define MB (1u << 20)

#define LDS_PTR(p) ((__attribute__((address_space(3))) void*)(p))
#define GLB_PTR(p) ((const __attribute__((address_space(1))) void*)(p))

__device__ __forceinline__ u16 f2bf(float f) {
  u32 u = __builtin_bit_cast(u32, f);
  u += 0x7FFFu + ((u >> 16) & 1u);   // RNE; inputs are finite
  return (u16)(u >> 16);
}
__device__ __forceinline__ float bf2f(u16 x) {
  u32 u = ((u32)x) << 16;
  return __builtin_bit_cast(float, u);
}
__device__ __forceinline__ u32 pack2(float a, float b) {
  return (u32)f2bf(a) | ((u32)f2bf(b) << 16);
}

// ---------------- K0: weights fp32 -> bf16 (5 x 1M elements, 2-wide) --------
__global__ __launch_bounds__(256) void prep_w(
    const float* __restrict__ w0, const float* __restrict__ w1,
    const float* __restrict__ w2, const float* __restrict__ w3,
    const float* __restrict__ w4, u32* __restrict__ out) {
  int idx = blockIdx.x * 256 + threadIdx.x;   // pair index, 5*524288 total
  int m = idx >> 19;                          // matrix id (uniform per block)
  int l = idx & 524287;
  const float* src = (m == 0) ? w0 : (m == 1) ? w1 : (m == 2) ? w2 : (m == 3) ? w3 : w4;
  float2 v = *(const float2*)(src + (size_t)l * 2);
  out[idx] = pack2(v.x, v.y);
}

// ---------------- K1: token-shift mix -> bf16 (2-wide) ----------------------
__global__ __launch_bounds__(256) void prep_mix(
    const float* __restrict__ x,
    const float* __restrict__ tmr, const float* __restrict__ tmk,
    const float* __restrict__ tmv, const float* __restrict__ tmw,
    u32* __restrict__ xr, u32* __restrict__ xk,
    u32* __restrict__ xv, u32* __restrict__ xw) {
  int idx = blockIdx.x * 256 + threadIdx.x;   // pair index over 4*1024*512
  int t  = (idx >> 9) & 1023;
  int d0 = (idx & 511) * 2;
  size_t e = (size_t)idx * 2;
  float2 xc = *(const float2*)(x + e);
  float2 xp = make_float2(0.f, 0.f);
  if (t > 0) xp = *(const float2*)(x + e - 1024);
  float2 tm;
  tm = *(const float2*)(tmr + d0);
  xr[idx] = pack2(tm.x * xc.x + (1.f - tm.x) * xp.x, tm.y * xc.y + (1.f - tm.y) * xp.y);
  tm = *(const float2*)(tmk + d0);
  xk[idx] = pack2(tm.x * xc.x + (1.f - tm.x) * xp.x, tm.y * xc.y + (1.f - tm.y) * xp.y);
  tm = *(const float2*)(tmv + d0);
  xv[idx] = pack2(tm.x * xc.x + (1.f - tm.x) * xp.x, tm.y * xc.y + (1.f - tm.y) * xp.y);
  tm = *(const float2*)(tmw + d0);
  xw[idx] = pack2(tm.x * xc.x + (1.f - tm.x) * xp.x, tm.y * xc.y + (1.f - tm.y) * xp.y);
}

// ---------------- GEMM core: C[m][n] = sum_k A[m][k]*W[n][k] ----------------
// Tile 128x128xBK32, 256 threads. TRIPLE-buffered global_load_lds pipeline,
// prefetch distance 3, steady-state wait vmcnt(8) — two tiles in flight
// across the barrier (R6's distance-2 regressed 2x on the same machine:
// depth is the lever). Raw s_barrier; lgkmcnt(0) before 2nd barrier.
// XOR-swizzled LDS (conflict-free).
// ACT: 0 none, 1 sigmoid, 2 -softplus(-z)-1e-4.  OBF: 1 -> store bf16.
template <int ACT, int OBF>
__device__ __forceinline__ void gemm_core(
    const u16* __restrict__ A, const u16* __restrict__ W, void* __restrict__ Optr,
    u16* Asm, u16* Bsm) {   // each 3*4096 u16 (3 x 8KB)
  int tid = threadIdx.x;
  int m0 = blockIdx.x * 128, n0 = blockIdx.y * 128;
  int wave = tid >> 6, lane = tid & 63;
  int wm = (wave >> 1) * 64, wn = (wave & 1) * 64;
  int r16 = lane & 15, quad = lane >> 4;

  f32x4 acc[4][4] = {};

  int srow0 = wave * 32 + (lane >> 2);
  int srow1 = srow0 + 16;
  int c4    = lane & 3;
  int q0 = c4 ^ ((srow0 >> 1) & 3);
  int q1 = c4 ^ ((srow1 >> 1) & 3);
  const u16* Ag0 = A + (size_t)(m0 + srow0) * 1024 + q0 * 8;
  const u16* Ag1 = A + (size_t)(m0 + srow1) * 1024 + q1 * 8;
  const u16* Bg0 = W + (size_t)(n0 + srow0) * 1024 + q0 * 8;
  const u16* Bg1 = W + (size_t)(n0 + srow1) * 1024 + q1 * 8;
  int ldsOff0 = wave * 1024;        // u16 offset within one 8KB buffer
  int ldsOff1 = wave * 1024 + 512;

  int aoff[4], boff[4];
#pragma unroll
  for (int mt = 0; mt < 4; ++mt) {
    int r = wm + mt * 16 + r16;
    aoff[mt] = r * 32 + (quad ^ ((r >> 1) & 3)) * 8;
  }
#pragma unroll
  for (int nt = 0; nt < 4; ++nt) {
    int r = wn + nt * 16 + r16;
    boff[nt] = r * 32 + (quad ^ ((r >> 1) & 3)) * 8;
  }

#define ISSUE_TILE(t, buf)                                                              \
  do {                                                                                  \
    int _o = (buf) * 4096, _k = (t) * 32;                                               \
    __builtin_amdgcn_global_load_lds(GLB_PTR(Ag0 + _k), LDS_PTR(Asm + _o + ldsOff0), 16, 0, 0); \
    __builtin_amdgcn_global_load_lds(GLB_PTR(Ag1 + _k), LDS_PTR(Asm + _o + ldsOff1), 16, 0, 0); \
    __builtin_amdgcn_global_load_lds(GLB_PTR(Bg0 + _k), LDS_PTR(Bsm + _o + ldsOff0), 16, 0, 0); \
    __builtin_amdgcn_global_load_lds(GLB_PTR(Bg1 + _k), LDS_PTR(Bsm + _o + ldsOff1), 16, 0, 0); \
  } while (0)

  // prologue: fill the 3-deep ring
  ISSUE_TILE(0, 0);
  ISSUE_TILE(1, 1);
  ISSUE_TILE(2, 2);

  int cur = 0;
  for (int i = 0; i < 32; ++i) {
    // wait only for tile i's 4 staging insts; newer tiles stay in flight
    if (i < 30)       asm volatile("s_waitcnt vmcnt(8)" ::: "memory");
    else if (i == 30) asm volatile("s_waitcnt vmcnt(4)" ::: "memory");
    else              asm volatile("s_waitcnt vmcnt(0)" ::: "memory");
    __builtin_amdgcn_s_barrier();   // all waves' tile-i data landed

    const u16* As = Asm + cur * 4096;
    const u16* Bs = Bsm + cur * 4096;
    bf16x8 af[4], bfm[4];
#pragma unroll
    for (int mt = 0; mt < 4; ++mt) af[mt] = *(const bf16x8*)&As[aoff[mt]];
#pragma unroll
    for (int nt = 0; nt < 4; ++nt) bfm[nt] = *(const bf16x8*)&Bs[boff[nt]];
#pragma unroll
    for (int mt = 0; mt < 4; ++mt)
#pragma unroll
      for (int nt = 0; nt < 4; ++nt)
        acc[mt][nt] = __builtin_amdgcn_mfma_f32_16x16x32_bf16(af[mt], bfm[nt], acc[mt][nt], 0, 0, 0);

    asm volatile("s_waitcnt lgkmcnt(0)" ::: "memory");  // my ds_reads done
    __builtin_amdgcn_s_barrier();                       // everyone's reads done
    if (i + 3 < 32) ISSUE_TILE(i + 3, cur);             // re-target freed buffer
    cur = (cur == 2) ? 0 : cur + 1;
  }
#undef ISSUE_TILE

  // epilogue: C/D layout col=lane&15, row=quad*4+reg  [verified m89/m91]
#pragma unroll
  for (int mt = 0; mt < 4; ++mt) {
#pragma unroll
    for (int nt = 0; nt < 4; ++nt) {
#pragma unroll
      for (int rg = 0; rg < 4; ++rg) {
        int row = m0 + wm + mt * 16 + quad * 4 + rg;
        int col = n0 + wn + nt * 16 + r16;
        float v = acc[mt][nt][rg];
        if (ACT == 1) v = 1.f / (1.f + __expf(-v));
        else if (ACT == 2) v = -(fmaxf(-v, 0.f) + log1pf(expf(-fabsf(v)))) - 1e-4f;
        size_t idx = (size_t)row * 1024 + col;
        if (OBF) ((u16*)Optr)[idx] = f2bf(v);
        else     ((float*)Optr)[idx] = v;
      }
    }
  }
}

// K2: four projection GEMMs in one launch (grid.z selects matrix)
__global__ __launch_bounds__(256) void gemm4_bt(
    const u16* __restrict__ xr, const u16* __restrict__ xk,
    const u16* __restrict__ xv, const u16* __restrict__ xw,
    const u16* __restrict__ Wr, const u16* __restrict__ Wk,
    const u16* __restrict__ Wv, const u16* __restrict__ Ww,
    u16* __restrict__ r, u16* __restrict__ k,
    u16* __restrict__ v, float* __restrict__ w) {
  __shared__ __align__(16) u16 Asm[3 * 4096];
  __shared__ __align__(16) u16 Bsm[3 * 4096];
  switch (blockIdx.z) {
    case 0:  gemm_core<1, 1>(xr, Wr, r, Asm, Bsm); break;   // r = sigmoid, bf16
    case 1:  gemm_core<0, 1>(xk, Wk, k, Asm, Bsm); break;   // k bf16
    case 2:  gemm_core<0, 1>(xv, Wv, v, Asm, Bsm); break;   // v bf16
    default: gemm_core<2, 0>(xw, Ww, w, Asm, Bsm); break;   // w fp32 (R5-exact)
  }
}

// K6: output GEMM
__global__ __launch_bounds__(256) void gemm_out(
    const u16* __restrict__ A, const u16* __restrict__ W, float* __restrict__ O) {
  __shared__ __align__(16) u16 Asm[3 * 4096];
  __shared__ __align__(16) u16 Bsm[3 * 4096];
  gemm_core<0, 0>(A, W, O, Asm, Bsm);
}

// ---------------- K3: intra-chunk scan, C=32, 4-step batching ---------------
// Block = (chunk c in [0,32), b*16+h), 256 threads = 4 i-groups x 64 j.
// Loader roles: w0 -> r (and rd/decay), w1 -> k(+euk), w2 -> v, w3 -> ew.
// 8-slot LDS ring (slot = t&7): stage steps tt+4..tt+7 while computing
// tt..tt+3. ONE barrier per 4 steps. o-stores deferred one interval and
// spread across waves (ig handles t = tt-4+ig). 2048 blocks -> 8/CU (full
// 32-wave occupancy) to cover LDS/stage latency; serial depth 32.
__global__ __launch_bounds__(256) void scan_intra(
    const u16* __restrict__ rb, const u16* __restrict__ kb,
    const u16* __restrict__ vb, const float* __restrict__ wb,
    const float* __restrict__ u,
    float* __restrict__ o, u16* __restrict__ rd,
    float* __restrict__ U, float* __restrict__ Dc) {
  int c = blockIdx.x, bh = blockIdx.y;
  int b = bh >> 4, h = bh & 15;
  int tid = threadIdx.x, ig = tid >> 6, j = tid & 63;

  __shared__ __align__(16) float4 combo[8][64];  // per-i: (r, k, exp(u+k), exp(w))
  __shared__ float vs_[8][64];
  __shared__ float part[8][4][64];

  float s[16];
#pragma unroll
  for (int ii = 0; ii < 16; ++ii) s[ii] = 0.f;

  size_t base = ((size_t)(b * 1024 + c * 32)) * 1024 + h * 64 + j;
  float dloc = 1.0f;
  float uval = (ig == 1) ? u[h * 64 + j] : 0.f;

  // prologue: stage steps 0..3 into slots 0..3
#pragma unroll
  for (int p = 0; p < 4; ++p) {
    size_t idx = base + (size_t)p * 1024;
    if (ig == 0)      combo[p][j].x = bf2f(rb[idx]);
    else if (ig == 1) { float kv = bf2f(kb[idx]); combo[p][j].y = kv; combo[p][j].z = __expf(uval + kv); }
    else if (ig == 2) vs_[p][j] = bf2f(vb[idx]);
    else              combo[p][j].w = __expf(wb[idx]);
  }
  __syncthreads();

  for (int tt = 0; tt < 32; tt += 4) {
    // stage steps tt+4..tt+7 (slots disjoint from compute slots this interval)
    if (tt + 4 < 32) {
#pragma unroll
      for (int p = 0; p < 4; ++p) {
        int t2 = tt + 4 + p, sl = t2 & 7;
        size_t idx = base + (size_t)t2 * 1024;
        if (ig == 0)      combo[sl][j].x = bf2f(rb[idx]);
        else if (ig == 1) { float kv = bf2f(kb[idx]); combo[sl][j].y = kv; combo[sl][j].z = __expf(uval + kv); }
        else if (ig == 2) vs_[sl][j] = bf2f(vb[idx]);
        else              combo[sl][j].w = __expf(wb[idx]);
      }
    }
    // compute steps tt..tt+3 (staged last interval; barrier crossed)
#pragma unroll
    for (int p = 0; p < 4; ++p) {
      int t = tt + p, sl = t & 7;
      float vj = vs_[sl][j];
      float acc = 0.f;
#pragma unroll
      for (int ii = 0; ii < 16; ++ii) {
        float4 cb = combo[sl][ig * 16 + ii];  // broadcast b128
        float tmp = fmaf(cb.z, vj, s[ii]);    // s + exp(u+k)*v
        acc = fmaf(cb.x, tmp, acc);           // += r * (...)
        s[ii] = fmaf(cb.w, s[ii], cb.y * vj); // s = exp(w)*s + k*v
      }
      part[sl][ig][j] = acc;
      if (ig == 0) {
        rd[base + (size_t)t * 1024] = f2bf(combo[sl][j].x * dloc);
        dloc *= combo[sl][j].w;
      }
    }
    // store o for steps tt-4..tt-1 (parts complete since last barrier);
    // wave ig handles step tt-4+ig.
    if (tt >= 4) {
      int t = tt - 4 + ig, sl = t & 7;
      o[base + (size_t)t * 1024] =
          part[sl][0][j] + part[sl][1][j] + part[sl][2][j] + part[sl][3][j];
    }
    __syncthreads();
  }
  // final interval's o: steps 28..31 (barrier at loop end crossed)
  {
    int t = 28 + ig, sl = t & 7;
    o[base + (size_t)t * 1024] =
        part[sl][0][j] + part[sl][1][j] + part[sl][2][j] + part[sl][3][j];
  }

  float* Ug = U + (size_t)(bh * 32 + c) * 4096;
#pragma unroll
  for (int ii = 0; ii < 16; ++ii) Ug[(ig * 16 + ii) * 64 + j] = s[ii];
  if (ig == 0) Dc[(bh * 32 + c) * 64 + j] = dloc;
}

// ---------------- K4: chunk-state propagation (per-element parallel) --------
// NC=32 sequential chunks per element; grid 64 bh x 16 segments.
__global__ __launch_bounds__(256) void state_prop(
    float* __restrict__ U, const float* __restrict__ Dc) {
  int bh  = blockIdx.x >> 4;
  int e   = (blockIdx.x & 15) * 256 + threadIdx.x;  // 0..4095
  int i   = e >> 6;                                 // state row (decay index)
  float acc = 0.f;
  for (int c = 0; c < 32; ++c) {
    float* Ug = U + (size_t)(bh * 32 + c) * 4096 + e;
    float d = Dc[(bh * 32 + c) * 64 + i];
    float uv = *Ug;
    *Ug = acc;                      // write S_c (chunk-initial state)
    acc = fmaf(d, acc, uv);         // S_{c+1} = D_c*S_c + U_c
  }
}

// ---------------- K5: O = o_intra + RD@S_c (MFMA) + group-LN + gate --------
// Block (cp in [0,16), bh) covers chunks 2cp, 2cp+1 (64 t-rows). 4 waves;
// wave w owns t-rows [w*16, w*16+16), chunk ci = w>>1 -> Sb[ci].
// S_c (fp32, [i][j]) transposed to bf16 LDS Sb[ci][j][i] (pad 72).
// A = rd[t][i] (bf16, global, K-contiguous). D[m=t][n=j] = sum_i rd*S.
__global__ __launch_bounds__(256) void inter_ln(
    const float* __restrict__ o, const u16* __restrict__ rd,
    const u16* __restrict__ rb, const float* __restrict__ U,
    const float* __restrict__ lnw, const float* __restrict__ lnb,
    u16* __restrict__ oh) {
  int cp = blockIdx.x, bh = blockIdx.y;
  int b = bh >> 4, h = bh & 15;
  int tid = threadIdx.x, wave = tid >> 6, lane = tid & 63;
  int l15 = lane & 15, quad = lane >> 4;

  __shared__ __align__(16) u16 Sb[2][64][72];   // Sb[ci][j][i] = S[i][j] (bf16)

  const float* Sg0 = U + (size_t)(bh * 32 + cp * 2) * 4096;
  const float* Sg1 = Sg0 + 4096;
#pragma unroll
  for (int q = 0; q < 16; ++q) {
    int e = q * 256 + tid;
    Sb[0][e & 63][e >> 6] = f2bf(Sg0[e]);
    Sb[1][e & 63][e >> 6] = f2bf(Sg1[e]);
  }
  __syncthreads();

  size_t rbase = ((size_t)(b * 1024 + cp * 64)) * 1024 + h * 64;
  int ci = wave >> 1;

  // A fragments: A[m=l15][k=quad*8+idx] (+32 for kt=1), m-strip = wave*16
  const u16* rdg = rd + rbase + (size_t)(wave * 16 + l15) * 1024 + quad * 8;
  bf16x8 af0 = *(const bf16x8*)(rdg);
  bf16x8 af1 = *(const bf16x8*)(rdg + 32);

  f32x4 acc[4] = {};
#pragma unroll
  for (int nt = 0; nt < 4; ++nt) {
    const u16* bp = &Sb[ci][nt * 16 + l15][quad * 8];
    bf16x8 b0 = *(const bf16x8*)bp;
    bf16x8 b1 = *(const bf16x8*)(bp + 32);
    acc[nt] = __builtin_amdgcn_mfma_f32_16x16x32_bf16(af0, b0, acc[nt], 0, 0, 0);
    acc[nt] = __builtin_amdgcn_mfma_f32_16x16x32_bf16(af1, b1, acc[nt], 0, 0, 0);
  }

  // epilogue: row t = wave*16 + quad*4 + rg; col j = nt*16 + l15.
#pragma unroll
  for (int rg = 0; rg < 4; ++rg) {
    int t = wave * 16 + quad * 4 + rg;
    size_t rowb = rbase + (size_t)t * 1024;
    float v[4];
    float s1 = 0.f, s2 = 0.f;
#pragma unroll
    for (int nt = 0; nt < 4; ++nt) {
      v[nt] = acc[nt][rg] + o[rowb + nt * 16 + l15];
      s1 += v[nt];
      s2 += v[nt] * v[nt];
    }
#pragma unroll
    for (int m = 1; m < 16; m <<= 1) {   // reduce across the quad's 16 lanes
      s1 += __shfl_xor(s1, m, 64);
      s2 += __shfl_xor(s2, m, 64);
    }
    float mu  = s1 * (1.f / 64.f);
    float var = s2 * (1.f / 64.f) - mu * mu;
    float rstd = rsqrtf(var + 1e-5f);
#pragma unroll
    for (int nt = 0; nt < 4; ++nt) {
      int jj = nt * 16 + l15;
      float nv = (v[nt] - mu) * rstd;
      float val = (nv * lnw[jj] + lnb[jj]) * bf2f(rb[rowb + jj]);
      oh[rowb + jj] = f2bf(val);
    }
  }
}

// ---------------- launch -----------------------------------------------------
extern "C" void kernel_launch(void* const* d_in, const int* in_sizes, int n_in,
                              void* d_out, int out_size, void* d_ws, size_t ws_size,
                              hipStream_t stream) {
  const float* x    = (const float*)d_in[0];
  const float* W_r  = (const float*)d_in[1];
  const float* W_k  = (const float*)d_in[2];
  const float* W_v  = (const float*)d_in[3];
  const float* W_w  = (const float*)d_in[4];
  const float* W_o  = (const float*)d_in[5];
  const float* u    = (const float*)d_in[6];
  const float* tm_r = (const float*)d_in[7];
  const float* tm_k = (const float*)d_in[8];
  const float* tm_v = (const float*)d_in[9];
  const float* tm_w = (const float*)d_in[10];
  const float* ln_w = (const float*)d_in[11];
  const float* ln_b = (const float*)d_in[12];
  float* out = (float*)d_out;

  char* ws = (char*)d_ws;
  u16* xr = (u16*)(ws + (size_t)0 * MB);
  u16* xk = (u16*)(ws + (size_t)8 * MB);
  u16* xv = (u16*)(ws + (size_t)16 * MB);
  u16* xw = (u16*)(ws + (size_t)24 * MB);
  u16* Wb = (u16*)(ws + (size_t)32 * MB);   // 5 x 2MB: Wr,Wk,Wv,Ww,Wo
  u16* Wrb = Wb;
  u16* Wkb = (u16*)(ws + (size_t)34 * MB);
  u16* Wvb = (u16*)(ws + (size_t)36 * MB);
  u16* Wwb = (u16*)(ws + (size_t)38 * MB);
  u16* Wob = (u16*)(ws + (size_t)40 * MB);
  u16*   rbuf = (u16*)(ws + (size_t)48 * MB);    // 8MB bf16
  u16*   kbuf = (u16*)(ws + (size_t)56 * MB);    // 8MB bf16
  u16*   vbuf = (u16*)(ws + (size_t)64 * MB);    // 8MB bf16
  float* wbuf = (float*)(ws + (size_t)72 * MB);  // 16MB fp32 (decay path)
  float* obuf = (float*)(ws + (size_t)88 * MB);  // 16MB fp32 o_intra
  u16*  rdbuf = (u16*)(ws + (size_t)104 * MB);   // 8MB bf16
  float* Ubuf  = (float*)(ws + (size_t)112 * MB);// 32MB (S_c after state_prop)
  float* Dcbuf = (float*)(ws + (size_t)144 * MB);// 512KB
  u16*   ohbuf = (u16*)(ws + (size_t)145 * MB);  // 8MB

  prep_w<<<10240, 256, 0, stream>>>(W_r, W_k, W_v, W_w, W_o, (u32*)Wb);
  prep_mix<<<8192, 256, 0, stream>>>(x, tm_r, tm_k, tm_v, tm_w,
                                     (u32*)xr, (u32*)xk, (u32*)xv, (u32*)xw);
  gemm4_bt<<<dim3(32, 8, 4), 256, 0, stream>>>(xr, xk, xv, xw,
                                               Wrb, Wkb, Wvb, Wwb,
                                               rbuf, kbuf, vbuf, wbuf);
  scan_intra<<<dim3(32, 64), 256, 0, stream>>>(rbuf, kbuf, vbuf, wbuf, u,
                                               obuf, rdbuf, Ubuf, Dcbuf);
  state_prop<<<1024, 256, 0, stream>>>(Ubuf, Dcbuf);
  inter_ln<<<dim3(16, 64), 256, 0, stream>>>(obuf, rdbuf, rbuf, Ubuf,
                                             ln_w, ln_b, ohbuf);
  gemm_out<<<dim3(32, 8, 1), 256, 0, stream>>>(ohbuf, Wob, out);
}

// Round 9
// 289.761 us; speedup vs baseline: 1.2777x; 1.2777x over previous
//
#include <hip/hip_runtime.h>

// RWKV6 TimeMix on MI355X — R9: asymmetric-depth GEMM ring (A=4-deep HBM
// stream, B=2-deep L2-hot weights; same 48KB LDS), all-bf16 intermediates.
//   K0 prep_w     : 5 weight matrices fp32 -> bf16
//   K1 prep_mix   : token-shift mix -> xr,xk,xv,xw (bf16)
//   K2 gemm4_bt   : 4x MFMA GEMM + activations -> r,k,v,w (bf16)
//   K3 scan_intra : chunked (C=32) scan -> o_intra (bf16), rd (bf16), U_c, D_c
//   K4 state_prop : S_{c+1} = D_c*S_c + U_c over NC=32 (U slot -> chunk-initial S_c)
//   K5 inter_ln   : O = o_intra + RD@S_c (MFMA, 2 chunks/block), LN, *r -> bf16
//   K6 gemm_out   : MFMA GEMM -> d_out (fp32)
//
// Machine note (R5 vs R8 forensics): identical GEMM code measured 77us
// (box ts~1.60e15) vs 164us (box ts~5.83e15) — slow boxes show ~2x memory
// latency (MfmaUtil/VALUBusy exactly halved, bytes identical). The A-ring
// depth-4 change below buys +50% latency slack at zero LDS/occupancy cost.
//
// Shapes: B=4, T=1024, D=1024, H=16, DH=64. Chunks: NC=32, C=32.

typedef unsigned short u16;
typedef unsigned int   u32;

typedef __attribute__((ext_vector_type(8))) __bf16 bf16x8;
typedef __attribute__((ext_vector_type(4))) float   f32x4;

#define MB (1u << 20)

#define LDS_PTR(p) ((__attribute__((address_space(3))) void*)(p))
#define GLB_PTR(p) ((const __attribute__((address_space(1))) void*)(p))

__device__ __forceinline__ u16 f2bf(float f) {
  u32 u = __builtin_bit_cast(u32, f);
  u += 0x7FFFu + ((u >> 16) & 1u);   // RNE; inputs are finite
  return (u16)(u >> 16);
}
__device__ __forceinline__ float bf2f(u16 x) {
  u32 u = ((u32)x) << 16;
  return __builtin_bit_cast(float, u);
}
__device__ __forceinline__ u32 pack2(float a, float b) {
  return (u32)f2bf(a) | ((u32)f2bf(b) << 16);
}

// ---------------- K0: weights fp32 -> bf16 (5 x 1M elements, 2-wide) --------
__global__ __launch_bounds__(256) void prep_w(
    const float* __restrict__ w0, const float* __restrict__ w1,
    const float* __restrict__ w2, const float* __restrict__ w3,
    const float* __restrict__ w4, u32* __restrict__ out) {
  int idx = blockIdx.x * 256 + threadIdx.x;   // pair index, 5*524288 total
  int m = idx >> 19;                          // matrix id (uniform per block)
  int l = idx & 524287;
  const float* src = (m == 0) ? w0 : (m == 1) ? w1 : (m == 2) ? w2 : (m == 3) ? w3 : w4;
  float2 v = *(const float2*)(src + (size_t)l * 2);
  out[idx] = pack2(v.x, v.y);
}

// ---------------- K1: token-shift mix -> bf16 (2-wide) ----------------------
__global__ __launch_bounds__(256) void prep_mix(
    const float* __restrict__ x,
    const float* __restrict__ tmr, const float* __restrict__ tmk,
    const float* __restrict__ tmv, const float* __restrict__ tmw,
    u32* __restrict__ xr, u32* __restrict__ xk,
    u32* __restrict__ xv, u32* __restrict__ xw) {
  int idx = blockIdx.x * 256 + threadIdx.x;   // pair index over 4*1024*512
  int t  = (idx >> 9) & 1023;
  int d0 = (idx & 511) * 2;
  size_t e = (size_t)idx * 2;
  float2 xc = *(const float2*)(x + e);
  float2 xp = make_float2(0.f, 0.f);
  if (t > 0) xp = *(const float2*)(x + e - 1024);
  float2 tm;
  tm = *(const float2*)(tmr + d0);
  xr[idx] = pack2(tm.x * xc.x + (1.f - tm.x) * xp.x, tm.y * xc.y + (1.f - tm.y) * xp.y);
  tm = *(const float2*)(tmk + d0);
  xk[idx] = pack2(tm.x * xc.x + (1.f - tm.x) * xp.x, tm.y * xc.y + (1.f - tm.y) * xp.y);
  tm = *(const float2*)(tmv + d0);
  xv[idx] = pack2(tm.x * xc.x + (1.f - tm.x) * xp.x, tm.y * xc.y + (1.f - tm.y) * xp.y);
  tm = *(const float2*)(tmw + d0);
  xw[idx] = pack2(tm.x * xc.x + (1.f - tm.x) * xp.x, tm.y * xc.y + (1.f - tm.y) * xp.y);
}

// ---------------- GEMM core: C[m][n] = sum_k A[m][k]*W[n][k] ----------------
// Tile 128x128xBK32, 256 threads. ASYMMETRIC ring: A (HBM stream) 4-deep,
// B (=W, L2-hot after first m-block) 2-deep; 48KB LDS total (3 blocks/CU).
// Issue order B-then-A each iter so vmcnt slack lands on A. Steady wait
// vmcnt(6): outstanding = A_{i+2},A_{i+3} (x2 each) + B_{i+1} (x2) — A gets
// ~3 iterations of latency slack (vs 2 in the symmetric depth-3 ring).
// Hand-verified wait schedule: i<2 -> 8; i<29 -> 6; 29 -> 4; 30 -> 2; 31 -> 0.
// Raw s_barrier; lgkmcnt(0) before 2nd barrier. XOR-swizzled LDS.
// ACT: 0 none, 1 sigmoid, 2 -softplus(-z)-1e-4.  OBF: 1 -> store bf16.
template <int ACT, int OBF>
__device__ __forceinline__ void gemm_core(
    const u16* __restrict__ A, const u16* __restrict__ W, void* __restrict__ Optr,
    u16* Asm, u16* Bsm) {   // Asm: 4*4096 u16 (32KB), Bsm: 2*4096 u16 (16KB)
  int tid = threadIdx.x;
  int m0 = blockIdx.x * 128, n0 = blockIdx.y * 128;
  int wave = tid >> 6, lane = tid & 63;
  int wm = (wave >> 1) * 64, wn = (wave & 1) * 64;
  int r16 = lane & 15, quad = lane >> 4;

  f32x4 acc[4][4] = {};

  int srow0 = wave * 32 + (lane >> 2);
  int srow1 = srow0 + 16;
  int c4    = lane & 3;
  int q0 = c4 ^ ((srow0 >> 1) & 3);
  int q1 = c4 ^ ((srow1 >> 1) & 3);
  const u16* Ag0 = A + (size_t)(m0 + srow0) * 1024 + q0 * 8;
  const u16* Ag1 = A + (size_t)(m0 + srow1) * 1024 + q1 * 8;
  const u16* Bg0 = W + (size_t)(n0 + srow0) * 1024 + q0 * 8;
  const u16* Bg1 = W + (size_t)(n0 + srow1) * 1024 + q1 * 8;
  int ldsOff0 = wave * 1024;        // u16 offset within one 8KB buffer
  int ldsOff1 = wave * 1024 + 512;

  int aoff[4], boff[4];
#pragma unroll
  for (int mt = 0; mt < 4; ++mt) {
    int r = wm + mt * 16 + r16;
    aoff[mt] = r * 32 + (quad ^ ((r >> 1) & 3)) * 8;
  }
#pragma unroll
  for (int nt = 0; nt < 4; ++nt) {
    int r = wn + nt * 16 + r16;
    boff[nt] = r * 32 + (quad ^ ((r >> 1) & 3)) * 8;
  }

#define ISSUE_A(t)                                                                      \
  do {                                                                                  \
    int _o = ((t) & 3) * 4096, _k = (t) * 32;                                           \
    __builtin_amdgcn_global_load_lds(GLB_PTR(Ag0 + _k), LDS_PTR(Asm + _o + ldsOff0), 16, 0, 0); \
    __builtin_amdgcn_global_load_lds(GLB_PTR(Ag1 + _k), LDS_PTR(Asm + _o + ldsOff1), 16, 0, 0); \
  } while (0)
#define ISSUE_B(t)                                                                      \
  do {                                                                                  \
    int _o = ((t) & 1) * 4096, _k = (t) * 32;                                           \
    __builtin_amdgcn_global_load_lds(GLB_PTR(Bg0 + _k), LDS_PTR(Bsm + _o + ldsOff0), 16, 0, 0); \
    __builtin_amdgcn_global_load_lds(GLB_PTR(Bg1 + _k), LDS_PTR(Bsm + _o + ldsOff1), 16, 0, 0); \
  } while (0)

  // prologue: A0,B0,A1,B1,A2,A3 (12 loads in flight)
  ISSUE_A(0);
  ISSUE_B(0);
  ISSUE_A(1);
  ISSUE_B(1);
  ISSUE_A(2);
  ISSUE_A(3);

  for (int i = 0; i < 32; ++i) {
    if (i < 2)        asm volatile("s_waitcnt vmcnt(8)" ::: "memory");
    else if (i < 29)  asm volatile("s_waitcnt vmcnt(6)" ::: "memory");
    else if (i == 29) asm volatile("s_waitcnt vmcnt(4)" ::: "memory");
    else if (i == 30) asm volatile("s_waitcnt vmcnt(2)" ::: "memory");
    else              asm volatile("s_waitcnt vmcnt(0)" ::: "memory");
    __builtin_amdgcn_s_barrier();   // all waves' tile-i data landed

    const u16* As = Asm + (i & 3) * 4096;
    const u16* Bs = Bsm + (i & 1) * 4096;
    bf16x8 af[4], bfm[4];
#pragma unroll
    for (int mt = 0; mt < 4; ++mt) af[mt] = *(const bf16x8*)&As[aoff[mt]];
#pragma unroll
    for (int nt = 0; nt < 4; ++nt) bfm[nt] = *(const bf16x8*)&Bs[boff[nt]];
#pragma unroll
    for (int mt = 0; mt < 4; ++mt)
#pragma unroll
      for (int nt = 0; nt < 4; ++nt)
        acc[mt][nt] = __builtin_amdgcn_mfma_f32_16x16x32_bf16(af[mt], bfm[nt], acc[mt][nt], 0, 0, 0);

    asm volatile("s_waitcnt lgkmcnt(0)" ::: "memory");  // my ds_reads done
    __builtin_amdgcn_s_barrier();                       // everyone's reads done
    if (i + 2 < 32) ISSUE_B(i + 2);   // B first: vmcnt slack stays on A
    if (i + 4 < 32) ISSUE_A(i + 4);
  }
#undef ISSUE_A
#undef ISSUE_B

  // epilogue: C/D layout col=lane&15, row=quad*4+reg  [verified m89/m91]
#pragma unroll
  for (int mt = 0; mt < 4; ++mt) {
#pragma unroll
    for (int nt = 0; nt < 4; ++nt) {
#pragma unroll
      for (int rg = 0; rg < 4; ++rg) {
        int row = m0 + wm + mt * 16 + quad * 4 + rg;
        int col = n0 + wn + nt * 16 + r16;
        float v = acc[mt][nt][rg];
        if (ACT == 1) v = 1.f / (1.f + __expf(-v));
        else if (ACT == 2) v = -(fmaxf(-v, 0.f) + log1pf(expf(-fabsf(v)))) - 1e-4f;
        size_t idx = (size_t)row * 1024 + col;
        if (OBF) ((u16*)Optr)[idx] = f2bf(v);
        else     ((float*)Optr)[idx] = v;
      }
    }
  }
}

// K2: four projection GEMMs in one launch (grid.z selects matrix)
__global__ __launch_bounds__(256) void gemm4_bt(
    const u16* __restrict__ xr, const u16* __restrict__ xk,
    const u16* __restrict__ xv, const u16* __restrict__ xw,
    const u16* __restrict__ Wr, const u16* __restrict__ Wk,
    const u16* __restrict__ Wv, const u16* __restrict__ Ww,
    u16* __restrict__ r, u16* __restrict__ k,
    u16* __restrict__ v, u16* __restrict__ w) {
  __shared__ __align__(16) u16 Asm[4 * 4096];
  __shared__ __align__(16) u16 Bsm[2 * 4096];
  switch (blockIdx.z) {
    case 0:  gemm_core<1, 1>(xr, Wr, r, Asm, Bsm); break;   // r = sigmoid, bf16
    case 1:  gemm_core<0, 1>(xk, Wk, k, Asm, Bsm); break;   // k bf16
    case 2:  gemm_core<0, 1>(xv, Wv, v, Asm, Bsm); break;   // v bf16
    default: gemm_core<2, 1>(xw, Ww, w, Asm, Bsm); break;   // w bf16 (R6/R7-proven safe)
  }
}

// K6: output GEMM
__global__ __launch_bounds__(256) void gemm_out(
    const u16* __restrict__ A, const u16* __restrict__ W, float* __restrict__ O) {
  __shared__ __align__(16) u16 Asm[4 * 4096];
  __shared__ __align__(16) u16 Bsm[2 * 4096];
  gemm_core<0, 0>(A, W, O, Asm, Bsm);
}

// ---------------- K3: intra-chunk scan, C=32, 4-step batching ---------------
// Block = (chunk c in [0,32), b*16+h), 256 threads = 4 i-groups x 64 j.
// Loader roles: w0 -> r (and rd/decay), w1 -> k(+euk), w2 -> v, w3 -> ew.
// 8-slot LDS ring (slot = t&7): stage steps tt+4..tt+7 while computing
// tt..tt+3. ONE barrier per 4 steps. o-stores deferred one interval and
// spread across waves. 2048 blocks -> 8/CU (18KB LDS) for latency cover.
__global__ __launch_bounds__(256) void scan_intra(
    const u16* __restrict__ rb, const u16* __restrict__ kb,
    const u16* __restrict__ vb, const u16* __restrict__ wb,
    const float* __restrict__ u,
    u16* __restrict__ o, u16* __restrict__ rd,
    float* __restrict__ U, float* __restrict__ Dc) {
  int c = blockIdx.x, bh = blockIdx.y;
  int b = bh >> 4, h = bh & 15;
  int tid = threadIdx.x, ig = tid >> 6, j = tid & 63;

  __shared__ __align__(16) float4 combo[8][64];  // per-i: (r, k, exp(u+k), exp(w))
  __shared__ float vs_[8][64];
  __shared__ float part[8][4][64];

  float s[16];
#pragma unroll
  for (int ii = 0; ii < 16; ++ii) s[ii] = 0.f;

  size_t base = ((size_t)(b * 1024 + c * 32)) * 1024 + h * 64 + j;
  float dloc = 1.0f;
  float uval = (ig == 1) ? u[h * 64 + j] : 0.f;

  // prologue: stage steps 0..3 into slots 0..3
#pragma unroll
  for (int p = 0; p < 4; ++p) {
    size_t idx = base + (size_t)p * 1024;
    if (ig == 0)      combo[p][j].x = bf2f(rb[idx]);
    else if (ig == 1) { float kv = bf2f(kb[idx]); combo[p][j].y = kv; combo[p][j].z = __expf(uval + kv); }
    else if (ig == 2) vs_[p][j] = bf2f(vb[idx]);
    else              combo[p][j].w = __expf(bf2f(wb[idx]));
  }
  __syncthreads();

  for (int tt = 0; tt < 32; tt += 4) {
    // stage steps tt+4..tt+7 (slots disjoint from compute slots this interval)
    if (tt + 4 < 32) {
#pragma unroll
      for (int p = 0; p < 4; ++p) {
        int t2 = tt + 4 + p, sl = t2 & 7;
        size_t idx = base + (size_t)t2 * 1024;
        if (ig == 0)      combo[sl][j].x = bf2f(rb[idx]);
        else if (ig == 1) { float kv = bf2f(kb[idx]); combo[sl][j].y = kv; combo[sl][j].z = __expf(uval + kv); }
        else if (ig == 2) vs_[sl][j] = bf2f(vb[idx]);
        else              combo[sl][j].w = __expf(bf2f(wb[idx]));
      }
    }
    // compute steps tt..tt+3 (staged last interval; barrier crossed)
#pragma unroll
    for (int p = 0; p < 4; ++p) {
      int t = tt + p, sl = t & 7;
      float vj = vs_[sl][j];
      float acc = 0.f;
#pragma unroll
      for (int ii = 0; ii < 16; ++ii) {
        float4 cb = combo[sl][ig * 16 + ii];  // broadcast b128
        float tmp = fmaf(cb.z, vj, s[ii]);    // s + exp(u+k)*v
        acc = fmaf(cb.x, tmp, acc);           // += r * (...)
        s[ii] = fmaf(cb.w, s[ii], cb.y * vj); // s = exp(w)*s + k*v
      }
      part[sl][ig][j] = acc;
      if (ig == 0) {
        rd[base + (size_t)t * 1024] = f2bf(combo[sl][j].x * dloc);
        dloc *= combo[sl][j].w;
      }
    }
    // store o for steps tt-4..tt-1 (parts complete since last barrier);
    // wave ig handles step tt-4+ig.
    if (tt >= 4) {
      int t = tt - 4 + ig, sl = t & 7;
      o[base + (size_t)t * 1024] =
          f2bf(part[sl][0][j] + part[sl][1][j] + part[sl][2][j] + part[sl][3][j]);
    }
    __syncthreads();
  }
  // final interval's o: steps 28..31 (barrier at loop end crossed)
  {
    int t = 28 + ig, sl = t & 7;
    o[base + (size_t)t * 1024] =
        f2bf(part[sl][0][j] + part[sl][1][j] + part[sl][2][j] + part[sl][3][j]);
  }

  float* Ug = U + (size_t)(bh * 32 + c) * 4096;
#pragma unroll
  for (int ii = 0; ii < 16; ++ii) Ug[(ig * 16 + ii) * 64 + j] = s[ii];
  if (ig == 0) Dc[(bh * 32 + c) * 64 + j] = dloc;
}

// ---------------- K4: chunk-state propagation (per-element parallel) --------
// NC=32 sequential chunks per element; grid 64 bh x 16 segments.
__global__ __launch_bounds__(256) void state_prop(
    float* __restrict__ U, const float* __restrict__ Dc) {
  int bh  = blockIdx.x >> 4;
  int e   = (blockIdx.x & 15) * 256 + threadIdx.x;  // 0..4095
  int i   = e >> 6;                                 // state row (decay index)
  float acc = 0.f;
  for (int c = 0; c < 32; ++c) {
    float* Ug = U + (size_t)(bh * 32 + c) * 4096 + e;
    float d = Dc[(bh * 32 + c) * 64 + i];
    float uv = *Ug;
    *Ug = acc;                      // write S_c (chunk-initial state)
    acc = fmaf(d, acc, uv);         // S_{c+1} = D_c*S_c + U_c
  }
}

// ---------------- K5: O = o_intra + RD@S_c (MFMA) + group-LN + gate --------
// Block (cp in [0,16), bh) covers chunks 2cp, 2cp+1 (64 t-rows). 4 waves;
// wave w owns t-rows [w*16, w*16+16), chunk ci = w>>1 -> Sb[ci].
// S_c (fp32, [i][j]) transposed to bf16 LDS Sb[ci][j][i] (pad 72).
// A = rd[t][i] (bf16, global, K-contiguous). D[m=t][n=j] = sum_i rd*S.
__global__ __launch_bounds__(256) void inter_ln(
    const u16* __restrict__ o, const u16* __restrict__ rd,
    const u16* __restrict__ rb, const float* __restrict__ U,
    const float* __restrict__ lnw, const float* __restrict__ lnb,
    u16* __restrict__ oh) {
  int cp = blockIdx.x, bh = blockIdx.y;
  int b = bh >> 4, h = bh & 15;
  int tid = threadIdx.x, wave = tid >> 6, lane = tid & 63;
  int l15 = lane & 15, quad = lane >> 4;

  __shared__ __align__(16) u16 Sb[2][64][72];   // Sb[ci][j][i] = S[i][j] (bf16)

  const float* Sg0 = U + (size_t)(bh * 32 + cp * 2) * 4096;
  const float* Sg1 = Sg0 + 4096;
#pragma unroll
  for (int q = 0; q < 16; ++q) {
    int e = q * 256 + tid;
    Sb[0][e & 63][e >> 6] = f2bf(Sg0[e]);
    Sb[1][e & 63][e >> 6] = f2bf(Sg1[e]);
  }
  __syncthreads();

  size_t rbase = ((size_t)(b * 1024 + cp * 64)) * 1024 + h * 64;
  int ci = wave >> 1;

  // A fragments: A[m=l15][k=quad*8+idx] (+32 for kt=1), m-strip = wave*16
  const u16* rdg = rd + rbase + (size_t)(wave * 16 + l15) * 1024 + quad * 8;
  bf16x8 af0 = *(const bf16x8*)(rdg);
  bf16x8 af1 = *(const bf16x8*)(rdg + 32);

  f32x4 acc[4] = {};
#pragma unroll
  for (int nt = 0; nt < 4; ++nt) {
    const u16* bp = &Sb[ci][nt * 16 + l15][quad * 8];
    bf16x8 b0 = *(const bf16x8*)bp;
    bf16x8 b1 = *(const bf16x8*)(bp + 32);
    acc[nt] = __builtin_amdgcn_mfma_f32_16x16x32_bf16(af0, b0, acc[nt], 0, 0, 0);
    acc[nt] = __builtin_amdgcn_mfma_f32_16x16x32_bf16(af1, b1, acc[nt], 0, 0, 0);
  }

  // epilogue: row t = wave*16 + quad*4 + rg; col j = nt*16 + l15.
#pragma unroll
  for (int rg = 0; rg < 4; ++rg) {
    int t = wave * 16 + quad * 4 + rg;
    size_t rowb = rbase + (size_t)t * 1024;
    float v[4];
    float s1 = 0.f, s2 = 0.f;
#pragma unroll
    for (int nt = 0; nt < 4; ++nt) {
      v[nt] = acc[nt][rg] + bf2f(o[rowb + nt * 16 + l15]);
      s1 += v[nt];
      s2 += v[nt] * v[nt];
    }
#pragma unroll
    for (int m = 1; m < 16; m <<= 1) {   // reduce across the quad's 16 lanes
      s1 += __shfl_xor(s1, m, 64);
      s2 += __shfl_xor(s2, m, 64);
    }
    float mu  = s1 * (1.f / 64.f);
    float var = s2 * (1.f / 64.f) - mu * mu;
    float rstd = rsqrtf(var + 1e-5f);
#pragma unroll
    for (int nt = 0; nt < 4; ++nt) {
      int jj = nt * 16 + l15;
      float nv = (v[nt] - mu) * rstd;
      float val = (nv * lnw[jj] + lnb[jj]) * bf2f(rb[rowb + jj]);
      oh[rowb + jj] = f2bf(val);
    }
  }
}

// ---------------- launch -----------------------------------------------------
extern "C" void kernel_launch(void* const* d_in, const int* in_sizes, int n_in,
                              void* d_out, int out_size, void* d_ws, size_t ws_size,
                              hipStream_t stream) {
  const float* x    = (const float*)d_in[0];
  const float* W_r  = (const float*)d_in[1];
  const float* W_k  = (const float*)d_in[2];
  const float* W_v  = (const float*)d_in[3];
  const float* W_w  = (const float*)d_in[4];
  const float* W_o  = (const float*)d_in[5];
  const float* u    = (const float*)d_in[6];
  const float* tm_r = (const float*)d_in[7];
  const float* tm_k = (const float*)d_in[8];
  const float* tm_v = (const float*)d_in[9];
  const float* tm_w = (const float*)d_in[10];
  const float* ln_w = (const float*)d_in[11];
  const float* ln_b = (const float*)d_in[12];
  float* out = (float*)d_out;

  char* ws = (char*)d_ws;
  u16* xr = (u16*)(ws + (size_t)0 * MB);
  u16* xk = (u16*)(ws + (size_t)8 * MB);
  u16* xv = (u16*)(ws + (size_t)16 * MB);
  u16* xw = (u16*)(ws + (size_t)24 * MB);
  u16* Wb = (u16*)(ws + (size_t)32 * MB);   // 5 x 2MB: Wr,Wk,Wv,Ww,Wo
  u16* Wrb = Wb;
  u16* Wkb = (u16*)(ws + (size_t)34 * MB);
  u16* Wvb = (u16*)(ws + (size_t)36 * MB);
  u16* Wwb = (u16*)(ws + (size_t)38 * MB);
  u16* Wob = (u16*)(ws + (size_t)40 * MB);
  u16*   rbuf = (u16*)(ws + (size_t)48 * MB);    // 8MB bf16
  u16*   kbuf = (u16*)(ws + (size_t)56 * MB);    // 8MB bf16
  u16*   vbuf = (u16*)(ws + (size_t)64 * MB);    // 8MB bf16
  u16*   wbuf = (u16*)(ws + (size_t)72 * MB);    // 8MB bf16
  u16*   obuf = (u16*)(ws + (size_t)80 * MB);    // 8MB bf16 o_intra
  u16*  rdbuf = (u16*)(ws + (size_t)88 * MB);    // 8MB bf16
  float* Ubuf  = (float*)(ws + (size_t)96 * MB); // 32MB (S_c after state_prop)
  float* Dcbuf = (float*)(ws + (size_t)128 * MB);// 512KB
  u16*   ohbuf = (u16*)(ws + (size_t)129 * MB);  // 8MB

  prep_w<<<10240, 256, 0, stream>>>(W_r, W_k, W_v, W_w, W_o, (u32*)Wb);
  prep_mix<<<8192, 256, 0, stream>>>(x, tm_r, tm_k, tm_v, tm_w,
                                     (u32*)xr, (u32*)xk, (u32*)xv, (u32*)xw);
  gemm4_bt<<<dim3(32, 8, 4), 256, 0, stream>>>(xr, xk, xv, xw,
                                               Wrb, Wkb, Wvb, Wwb,
                                               rbuf, kbuf, vbuf, wbuf);
  scan_intra<<<dim3(32, 64), 256, 0, stream>>>(rbuf, kbuf, vbuf, wbuf, u,
                                               obuf, rdbuf, Ubuf, Dcbuf);
  state_prop<<<1024, 256, 0, stream>>>(Ubuf, Dcbuf);
  inter_ln<<<dim3(16, 64), 256, 0, stream>>>(obuf, rdbuf, rbuf, Ubuf,
                                             ln_w, ln_b, ohbuf);
  gemm_out<<<dim3(32, 8, 1), 256, 0, stream>>>(ohbuf, Wob, out);
}